// Round 6
// baseline (423.774 us; speedup 1.0000x reference)
//
#include <hip/hip_runtime.h>
#include <math.h>

// Problem constants (reference: B=1, N=64, Q=K=512, C_Q=C_K=C_V=256, H=8, c=32)
#define NSEQ   64
#define QLEN   512
#define KLEN   512
#define CIN    256
#define HEADS  8
#define CH     32
#define HIDDIM 256
#define M_TOTAL (NSEQ * QLEN)   // 32768 rows for all projections

typedef _Float16 f16x8 __attribute__((ext_vector_type(8)));
typedef _Float16 f16x4 __attribute__((ext_vector_type(4)));
typedef __fp16   fp16x2 __attribute__((ext_vector_type(2)));   // cvt_pkrtz native type
typedef float    f32x4 __attribute__((ext_vector_type(4)));

// ---------------------------------------------------------------------------
// Weight transpose+cast: W[256 in][256 out] fp32 -> WT[256 out][256 in] fp16.
// ---------------------------------------------------------------------------
__global__ __launch_bounds__(256) void wcast_kernel(
    const float* __restrict__ w0, const float* __restrict__ w1,
    const float* __restrict__ w2, const float* __restrict__ w3,
    const float* __restrict__ w4, _Float16* __restrict__ wt)
{
    __shared__ float t[64][65];
    const float* W;
    switch (blockIdx.z) {
        case 0: W = w0; break; case 1: W = w1; break;
        case 2: W = w2; break; case 3: W = w3; break;
        default: W = w4;
    }
    _Float16* WT = wt + (size_t)blockIdx.z * 65536;
    const int i0 = blockIdx.x * 64, o0 = blockIdx.y * 64;
    const int tid = threadIdx.x;
    const int rr = tid >> 4, c4 = tid & 15;
    #pragma unroll
    for (int i = 0; i < 4; ++i) {
        const int row = rr + i * 16;
        *(float4*)&t[row][c4 * 4] = *(const float4*)&W[(size_t)(i0 + row) * 256 + o0 + c4 * 4];
    }
    __syncthreads();
    #pragma unroll
    for (int i = 0; i < 4; ++i) {
        const int row = rr + i * 16;            // out-dim row
        f16x4 v;
        #pragma unroll
        for (int j = 0; j < 4; ++j) v[j] = (_Float16)t[c4 * 4 + j][row];
        *(f16x4*)&WT[(size_t)(o0 + row) * 256 + i0 + c4 * 4] = v;
    }
}

// ---------------------------------------------------------------------------
// bias_pair -> MFMA-fragment order:
// bp_frag[((h*32+qt)*32+kt)*256 + lane*4 + reg] = bias_pair[h][qt*16+l15][kt*16+quad*4+reg]
// (lane = quad*16 + l15). Makes the attention bias read one coalesced float4.
// Grid (8 qb, 8 kb, 8 h): 64x64 region per block through LDS.
// ---------------------------------------------------------------------------
__global__ __launch_bounds__(256) void bpfrag_kernel(
    const float* __restrict__ bias_pair, float* __restrict__ frag)
{
    __shared__ float t[64][68];
    const int qb = blockIdx.x, kb = blockIdx.y, h = blockIdx.z;
    const int tid = threadIdx.x;
    #pragma unroll
    for (int i = 0; i < 4; ++i) {
        const int idx = tid + i * 256;
        const int r = idx >> 4, c4 = idx & 15;
        *(float4*)&t[r][c4 * 4] = *(const float4*)
            &bias_pair[((size_t)h * QLEN + qb * 64 + r) * KLEN + kb * 64 + c4 * 4];
    }
    __syncthreads();
    const int lane = tid & 63, w = tid >> 6;
    const int l15 = lane & 15, quad = lane >> 4;
    const int qt = qb * 4 + w;
    #pragma unroll
    for (int kt2 = 0; kt2 < 4; ++kt2) {
        const int kt = kb * 4 + kt2;
        float4 v;
        v.x = t[w * 16 + l15][kt2 * 16 + quad * 4 + 0];
        v.y = t[w * 16 + l15][kt2 * 16 + quad * 4 + 1];
        v.z = t[w * 16 + l15][kt2 * 16 + quad * 4 + 2];
        v.w = t[w * 16 + l15][kt2 * 16 + quad * 4 + 3];
        *(float4*)&frag[(((size_t)(h * 32 + qt) * 32) + kt) * 256 + lane * 4] = v;
    }
}

// ---------------------------------------------------------------------------
// Fused projection GEMM: z = 0:q (scale 1/sqrt32), 1:k, 2:v, 3:g (sigmoid+bg).
// ---------------------------------------------------------------------------
__global__ __launch_bounds__(256, 4) void proj_gemm_kernel(
    const float* __restrict__ q_x, const float* __restrict__ k_x,
    const float* __restrict__ v_x, const _Float16* __restrict__ wT,
    const float* __restrict__ bg,
    _Float16* __restrict__ oq, _Float16* __restrict__ ok,
    _Float16* __restrict__ ov, _Float16* __restrict__ og)
{
    __shared__ _Float16 A_s[128][72];   // stride 72 f16 = 144B ≡ 4 banks mod 32
    __shared__ _Float16 B_s[128][72];
    const int z = blockIdx.z;
    const float* A = (z == 1) ? k_x : (z == 2) ? v_x : q_x;
    const _Float16* BT = wT + (size_t)z * 65536;
    _Float16* C = (z == 0) ? oq : (z == 1) ? ok : (z == 2) ? ov : og;
    const float scale = (z == 0) ? 0.17677669529663689f : 1.0f;

    const int m0 = blockIdx.x * 128, n0 = blockIdx.y * 128;
    const int tid = threadIdx.x;
    const int lane = tid & 63, w = tid >> 6;
    const int l15 = lane & 15, quad = lane >> 4;
    const int mw = (w & 1) * 64, nw = (w >> 1) * 64;

    f32x4 acc[4][4];
    #pragma unroll
    for (int mt = 0; mt < 4; ++mt)
        #pragma unroll
        for (int nt = 0; nt < 4; ++nt) acc[mt][nt] = (f32x4){0.f, 0.f, 0.f, 0.f};

    for (int k0 = 0; k0 < CIN; k0 += 64) {
        __syncthreads();
        #pragma unroll
        for (int it = 0; it < 4; ++it) {
            const int idx = tid + it * 256;     // 0..1023
            const int r = idx >> 3, seg = idx & 7;
            const float* ap = A + (size_t)(m0 + r) * CIN + k0 + seg * 8;
            const float4 f0 = *(const float4*)ap;
            const float4 f1 = *(const float4*)(ap + 4);
            f16x8 v;
            v[0] = (_Float16)f0.x; v[1] = (_Float16)f0.y;
            v[2] = (_Float16)f0.z; v[3] = (_Float16)f0.w;
            v[4] = (_Float16)f1.x; v[5] = (_Float16)f1.y;
            v[6] = (_Float16)f1.z; v[7] = (_Float16)f1.w;
            *(f16x8*)&A_s[r][seg * 8] = v;
            *(uint4*)&B_s[r][seg * 8] =
                *(const uint4*)(BT + (size_t)(n0 + r) * CIN + k0 + seg * 8);
        }
        __syncthreads();
        #pragma unroll
        for (int ks = 0; ks < 2; ++ks) {
            f16x8 af[4], bf[4];
            #pragma unroll
            for (int mt = 0; mt < 4; ++mt)
                af[mt] = *(const f16x8*)&A_s[mw + mt * 16 + l15][ks * 32 + quad * 8];
            #pragma unroll
            for (int nt = 0; nt < 4; ++nt)
                bf[nt] = *(const f16x8*)&B_s[nw + nt * 16 + l15][ks * 32 + quad * 8];
            #pragma unroll
            for (int mt = 0; mt < 4; ++mt)
                #pragma unroll
                for (int nt = 0; nt < 4; ++nt)
                    acc[mt][nt] = __builtin_amdgcn_mfma_f32_16x16x32_f16(
                        af[mt], bf[nt], acc[mt][nt], 0, 0, 0);
        }
    }

    #pragma unroll
    for (int mt = 0; mt < 4; ++mt) {
        #pragma unroll
        for (int nt = 0; nt < 4; ++nt) {
            const int col = n0 + nw + nt * 16 + l15;
            const int rowb = m0 + mw + mt * 16 + quad * 4;
            #pragma unroll
            for (int reg = 0; reg < 4; ++reg) {
                float x = acc[mt][nt][reg] * scale;
                if (z == 3) {
                    x += bg[col];
                    x = 1.0f / (1.0f + __expf(-x));
                }
                C[(size_t)(rowb + reg) * HIDDIM + col] = (_Float16)x;
            }
        }
    }
}

// ---------------------------------------------------------------------------
// Generic MFMA GEMM — final output projection (fp16 in, fp32 out + bias).
// ---------------------------------------------------------------------------
__global__ __launch_bounds__(256, 4) void gemm_mfma_kernel(
    const _Float16* __restrict__ Ain, const _Float16* __restrict__ BT,
    const float* __restrict__ bias, float* __restrict__ Cout)
{
    __shared__ _Float16 A_s[128][72];
    __shared__ _Float16 B_s[128][72];
    const int m0 = blockIdx.x * 128, n0 = blockIdx.y * 128;
    const int tid = threadIdx.x;
    const int lane = tid & 63, w = tid >> 6;
    const int l15 = lane & 15, quad = lane >> 4;
    const int mw = (w & 1) * 64, nw = (w >> 1) * 64;

    f32x4 acc[4][4];
    #pragma unroll
    for (int mt = 0; mt < 4; ++mt)
        #pragma unroll
        for (int nt = 0; nt < 4; ++nt) acc[mt][nt] = (f32x4){0.f, 0.f, 0.f, 0.f};

    for (int k0 = 0; k0 < CIN; k0 += 64) {
        __syncthreads();
        #pragma unroll
        for (int it = 0; it < 4; ++it) {
            const int idx = tid + it * 256;
            const int r = idx >> 3, seg = idx & 7;
            *(uint4*)&A_s[r][seg * 8] =
                *(const uint4*)(Ain + (size_t)(m0 + r) * CIN + k0 + seg * 8);
            *(uint4*)&B_s[r][seg * 8] =
                *(const uint4*)(BT + (size_t)(n0 + r) * CIN + k0 + seg * 8);
        }
        __syncthreads();
        #pragma unroll
        for (int ks = 0; ks < 2; ++ks) {
            f16x8 af[4], bf[4];
            #pragma unroll
            for (int mt = 0; mt < 4; ++mt)
                af[mt] = *(const f16x8*)&A_s[mw + mt * 16 + l15][ks * 32 + quad * 8];
            #pragma unroll
            for (int nt = 0; nt < 4; ++nt)
                bf[nt] = *(const f16x8*)&B_s[nw + nt * 16 + l15][ks * 32 + quad * 8];
            #pragma unroll
            for (int mt = 0; mt < 4; ++mt)
                #pragma unroll
                for (int nt = 0; nt < 4; ++nt)
                    acc[mt][nt] = __builtin_amdgcn_mfma_f32_16x16x32_f16(
                        af[mt], bf[nt], acc[mt][nt], 0, 0, 0);
        }
    }

    #pragma unroll
    for (int mt = 0; mt < 4; ++mt) {
        #pragma unroll
        for (int nt = 0; nt < 4; ++nt) {
            const int col = n0 + nw + nt * 16 + l15;
            const int rowb = m0 + mw + mt * 16 + quad * 4;
            #pragma unroll
            for (int reg = 0; reg < 4; ++reg) {
                const float x = acc[mt][nt][reg] + bias[col];
                Cout[(size_t)(rowb + reg) * HIDDIM + col] = x;
            }
        }
    }
}

// ---------------------------------------------------------------------------
// V transpose: v[n*512+k][h*32+c] fp16 -> vT[(n*8+h)*32+c][k 512] fp16.
// ---------------------------------------------------------------------------
__global__ __launch_bounds__(256) void vtrans_kernel(
    const _Float16* __restrict__ v, _Float16* __restrict__ vT)
{
    __shared__ _Float16 t[32][72];
    const int nh = blockIdx.x;
    const int n = nh >> 3, h = nh & 7;
    const int tid = threadIdx.x;
    for (int kc = 0; kc < KLEN; kc += 64) {
        __syncthreads();
        const int r = tid >> 2, c8 = (tid & 3) * 8;
        const f16x8 vv = *(const f16x8*)(v + (size_t)(n * KLEN + kc + r) * HIDDIM + h * CH + c8);
        #pragma unroll
        for (int j = 0; j < 8; ++j) t[c8 + j][r] = vv[j];
        __syncthreads();
        const int c = tid >> 3, k8 = (tid & 7) * 8;
        const f16x8 o = *(const f16x8*)&t[c][k8];
        *(f16x8*)(vT + ((size_t)nh * CH + c) * KLEN + kc + k8) = o;
    }
}

// ---------------------------------------------------------------------------
// MFMA flash attention, register-P (S^T trick), LDS-staged K/V, fragment-
// ordered bias_pair. Block = (n, h, 128 q-rows), 4 waves, 32 q-rows/wave.
// K/V chunks of 128 staged coalesced; inner loop reads LDS + 3 coalesced
// global float4s only (was ~84 L1 segments/iter -> ~20).
// ---------------------------------------------------------------------------
__global__ __launch_bounds__(256, 8) void attn_kernel(
    const _Float16* __restrict__ qb, const _Float16* __restrict__ kb,
    const _Float16* __restrict__ vT, const _Float16* __restrict__ gb,
    _Float16* __restrict__ ob,
    const float* __restrict__ bias_mask, const float* __restrict__ bp_frag)
{
    __shared__ _Float16 k_s[128][40];    // 80B rows ≡ 20 banks mod 32
    __shared__ _Float16 v_s[32][136];    // [c][k], 272B rows ≡ 4 banks mod 32

    const int n    = blockIdx.x;
    const int h    = blockIdx.y;
    const int q0   = blockIdx.z * 128;
    const int tid  = threadIdx.x;
    const int lane = tid & 63;
    const int wq   = tid >> 6;            // wave id: q-band = wq*32
    const int l15  = lane & 15;
    const int quad = lane >> 4;

    // Q fragments (B-operand of S^T): row q0+wq*32+qt*16+l15, cols quad*8..+7
    f16x8 qf[2];
    #pragma unroll
    for (int qt = 0; qt < 2; ++qt)
        qf[qt] = *(const f16x8*)(qb +
            (size_t)(n * QLEN + q0 + wq * 32 + qt * 16 + l15) * HIDDIM + h * CH + quad * 8);

    // Fragment-ordered bias base for this wave's first q-tile (qt adds 32*256).
    const float* bpf = bp_frag +
        ((size_t)(h * 32 + blockIdx.z * 8 + wq * 2) * 32) * 256 + lane * 4;
    const float* bmb = bias_mask + n * KLEN + quad * 4;

    f32x4 o_acc[2][2];
    float l_lane[2] = {0.f, 0.f};
    #pragma unroll
    for (int qt = 0; qt < 2; ++qt)
        #pragma unroll
        for (int ct = 0; ct < 2; ++ct) o_acc[qt][ct] = (f32x4){0.f, 0.f, 0.f, 0.f};

    const f32x4 z4 = (f32x4){0.f, 0.f, 0.f, 0.f};

    for (int ch = 0; ch < 4; ++ch) {
        __syncthreads();   // previous chunk fully consumed
        // Stage K chunk [128][32] and V chunk [32][128] (from pre-transposed vT),
        // both fully coalesced 16B/lane.
        #pragma unroll
        for (int i = 0; i < 2; ++i) {
            const int idx = tid + i * 256;
            const int r = idx >> 2, c8 = idx & 3;
            *(uint4*)&k_s[r][c8 * 8] = *(const uint4*)
                (kb + (size_t)(n * KLEN + ch * 128 + r) * HIDDIM + h * CH + c8 * 8);
            const int vr = idx >> 4, vs = idx & 15;
            *(uint4*)&v_s[vr][vs * 8] = *(const uint4*)
                (vT + ((size_t)(n * HEADS + h) * CH + vr) * KLEN + ch * 128 + vs * 8);
        }
        __syncthreads();

        #pragma unroll
        for (int kt = 0; kt < 8; ++kt) {
            const int kti = ch * 8 + kt;
            // K fragment (A-operand of S^T) from LDS.
            const f16x8 kf = *(const f16x8*)&k_s[kt * 16 + l15][quad * 8];
            const f32x4 s0 = __builtin_amdgcn_mfma_f32_16x16x32_f16(kf, qf[0], z4, 0, 0, 0);
            const f32x4 s1 = __builtin_amdgcn_mfma_f32_16x16x32_f16(kf, qf[1], z4, 0, 0, 0);
            const float4 bm = *(const float4*)(bmb + ch * 128 + kt * 16);
            // V fragments (B-operand of PV, K=16): k = quad*4+j, c = ct*16+l15
            const f16x4 bv0 = *(const f16x4*)&v_s[l15][kt * 16 + quad * 4];
            const f16x4 bv1 = *(const f16x4*)&v_s[16 + l15][kt * 16 + quad * 4];
            #pragma unroll
            for (int qt = 0; qt < 2; ++qt) {
                const f32x4 s = qt ? s1 : s0;
                const float4 bp = *(const float4*)(bpf + ((size_t)qt * 32 + kti) * 256);
                const float p0 = __expf(s[0] + bm.x + bp.x - 4.0f);
                const float p1 = __expf(s[1] + bm.y + bp.y - 4.0f);
                const float p2 = __expf(s[2] + bm.z + bp.z - 4.0f);
                const float p3 = __expf(s[3] + bm.w + bp.w - 4.0f);
                l_lane[qt] += (p0 + p1) + (p2 + p3);
                union { f16x4 v; fp16x2 h[2]; } u;
                u.h[0] = __builtin_amdgcn_cvt_pkrtz(p0, p1);
                u.h[1] = __builtin_amdgcn_cvt_pkrtz(p2, p3);
                o_acc[qt][0] = __builtin_amdgcn_mfma_f32_16x16x16f16(u.v, bv0, o_acc[qt][0], 0, 0, 0);
                o_acc[qt][1] = __builtin_amdgcn_mfma_f32_16x16x16f16(u.v, bv1, o_acc[qt][1], 0, 0, 0);
            }
        }
    }

    // Reduce l across quads (full row sum for q = qt*16+l15), then fetch the
    // values for this lane's OUTPUT rows (q = quad*4+reg) via shuffles.
    float invl[2][4];
    #pragma unroll
    for (int qt = 0; qt < 2; ++qt) {
        float lf = l_lane[qt];
        lf += __shfl_xor(lf, 16);
        lf += __shfl_xor(lf, 32);
        #pragma unroll
        for (int reg = 0; reg < 4; ++reg)
            invl[qt][reg] = 1.0f / __shfl(lf, quad * 4 + reg);
    }

    // Epilogue: O D-layout col=l15 -> c, row=quad*4+reg -> q. Gate + store.
    #pragma unroll
    for (int qt = 0; qt < 2; ++qt) {
        #pragma unroll
        for (int ct = 0; ct < 2; ++ct) {
            #pragma unroll
            for (int reg = 0; reg < 4; ++reg) {
                const int row = q0 + wq * 32 + qt * 16 + quad * 4 + reg;
                const size_t idx = (size_t)(n * QLEN + row) * HIDDIM + h * CH + ct * 16 + l15;
                const float g = (float)gb[idx];
                ob[idx] = (_Float16)(o_acc[qt][ct][reg] * invl[qt][reg] * g);
            }
        }
    }
}

// ---------------------------------------------------------------------------
// Launch: wcast + bpfrag -> projections -> V transpose -> attention -> out GEMM.
// Workspace: 6 x 16.8 MB fp16 + 0.66 MB weights + 8.4 MB bp_frag = 110 MB
// ---------------------------------------------------------------------------
extern "C" void kernel_launch(void* const* d_in, const int* in_sizes, int n_in,
                              void* d_out, int out_size, void* d_ws, size_t ws_size,
                              hipStream_t stream)
{
    const float* q_x       = (const float*)d_in[0];
    const float* k_x       = (const float*)d_in[1];
    const float* v_x       = (const float*)d_in[2];
    const float* bias_mask = (const float*)d_in[3];
    const float* bias_pair = (const float*)d_in[4];
    const float* wq        = (const float*)d_in[5];
    const float* wk        = (const float*)d_in[6];
    const float* wv        = (const float*)d_in[7];
    const float* wg        = (const float*)d_in[8];
    const float* bg        = (const float*)d_in[9];
    const float* wo        = (const float*)d_in[10];
    const float* bo        = (const float*)d_in[11];
    float* out = (float*)d_out;

    const size_t BUF = (size_t)M_TOTAL * HIDDIM;   // 8388608 elems
    _Float16* ws_q  = (_Float16*)d_ws;
    _Float16* ws_k  = ws_q + BUF;
    _Float16* ws_v  = ws_k + BUF;
    _Float16* ws_vT = ws_v + BUF;
    _Float16* ws_g  = ws_vT + BUF;
    _Float16* ws_o  = ws_g + BUF;
    _Float16* wT    = ws_o + BUF;                  // 5 x 256*256 fp16
    float*    bpf   = (float*)(wT + 5 * 65536);    // 8 x 512 x 512 fp32 frag-ordered

    wcast_kernel<<<dim3(4, 4, 5), 256, 0, stream>>>(wq, wk, wv, wg, wo, wT);
    bpfrag_kernel<<<dim3(8, 8, 8), 256, 0, stream>>>(bias_pair, bpf);

    proj_gemm_kernel<<<dim3(M_TOTAL / 128, 2, 4), 256, 0, stream>>>(
        q_x, k_x, v_x, wT, bg, ws_q, ws_k, ws_v, ws_g);

    vtrans_kernel<<<dim3(NSEQ * HEADS), 256, 0, stream>>>(ws_v, ws_vT);

    attn_kernel<<<dim3(NSEQ, HEADS, QLEN / 128), 256, 0, stream>>>(
        ws_q, ws_k, ws_vT, ws_g, ws_o, bias_mask, bpf);

    gemm_mfma_kernel<<<dim3(M_TOTAL / 128, 2), 256, 0, stream>>>(
        ws_o, wT + 4 * 65536, bo, out);
}

// Round 7
// 290.581 us; speedup vs baseline: 1.4584x; 1.4584x over previous
//
#include <hip/hip_runtime.h>
#include <math.h>

// Problem constants (reference: B=1, N=64, Q=K=512, C_Q=C_K=C_V=256, H=8, c=32)
#define NSEQ   64
#define QLEN   512
#define KLEN   512
#define CIN    256
#define HEADS  8
#define CH     32
#define HIDDIM 256
#define M_TOTAL (NSEQ * QLEN)   // 32768 rows for all projections

typedef _Float16 f16x8 __attribute__((ext_vector_type(8)));
typedef _Float16 f16x4 __attribute__((ext_vector_type(4)));
typedef __fp16   fp16x2 __attribute__((ext_vector_type(2)));   // cvt_pkrtz native type
typedef float    f32x4 __attribute__((ext_vector_type(4)));

// ---------------------------------------------------------------------------
// Weight transpose+cast: W[256 in][256 out] fp32 -> WT[256 out][256 in] fp16.
// ---------------------------------------------------------------------------
__global__ __launch_bounds__(256) void wcast_kernel(
    const float* __restrict__ w0, const float* __restrict__ w1,
    const float* __restrict__ w2, const float* __restrict__ w3,
    const float* __restrict__ w4, _Float16* __restrict__ wt)
{
    __shared__ float t[64][65];
    const float* W;
    switch (blockIdx.z) {
        case 0: W = w0; break; case 1: W = w1; break;
        case 2: W = w2; break; case 3: W = w3; break;
        default: W = w4;
    }
    _Float16* WT = wt + (size_t)blockIdx.z * 65536;
    const int i0 = blockIdx.x * 64, o0 = blockIdx.y * 64;
    const int tid = threadIdx.x;
    const int rr = tid >> 4, c4 = tid & 15;
    #pragma unroll
    for (int i = 0; i < 4; ++i) {
        const int row = rr + i * 16;
        *(float4*)&t[row][c4 * 4] = *(const float4*)&W[(size_t)(i0 + row) * 256 + o0 + c4 * 4];
    }
    __syncthreads();
    #pragma unroll
    for (int i = 0; i < 4; ++i) {
        const int row = rr + i * 16;            // out-dim row
        f16x4 v;
        #pragma unroll
        for (int j = 0; j < 4; ++j) v[j] = (_Float16)t[c4 * 4 + j][row];
        *(f16x4*)&WT[(size_t)(o0 + row) * 256 + i0 + c4 * 4] = v;
    }
}

// ---------------------------------------------------------------------------
// bias_pair -> MFMA-fragment order:
// bp_frag[((h*32+qt)*32+kt)*256 + lane*4 + reg] = bias_pair[h][qt*16+l15][kt*16+quad*4+reg]
// (lane = quad*16 + l15). Makes the attention bias read one coalesced float4.
// ---------------------------------------------------------------------------
__global__ __launch_bounds__(256) void bpfrag_kernel(
    const float* __restrict__ bias_pair, float* __restrict__ frag)
{
    __shared__ float t[64][68];
    const int qb = blockIdx.x, kb = blockIdx.y, h = blockIdx.z;
    const int tid = threadIdx.x;
    #pragma unroll
    for (int i = 0; i < 4; ++i) {
        const int idx = tid + i * 256;
        const int r = idx >> 4, c4 = idx & 15;
        *(float4*)&t[r][c4 * 4] = *(const float4*)
            &bias_pair[((size_t)h * QLEN + qb * 64 + r) * KLEN + kb * 64 + c4 * 4];
    }
    __syncthreads();
    const int lane = tid & 63, w = tid >> 6;
    const int l15 = lane & 15, quad = lane >> 4;
    const int qt = qb * 4 + w;
    #pragma unroll
    for (int kt2 = 0; kt2 < 4; ++kt2) {
        const int kt = kb * 4 + kt2;
        float4 v;
        v.x = t[w * 16 + l15][kt2 * 16 + quad * 4 + 0];
        v.y = t[w * 16 + l15][kt2 * 16 + quad * 4 + 1];
        v.z = t[w * 16 + l15][kt2 * 16 + quad * 4 + 2];
        v.w = t[w * 16 + l15][kt2 * 16 + quad * 4 + 3];
        *(float4*)&frag[(((size_t)(h * 32 + qt) * 32) + kt) * 256 + lane * 4] = v;
    }
}

// ---------------------------------------------------------------------------
// Fused projection GEMM: z = 0:q (scale 1/sqrt32), 1:k, 2:v, 3:g (sigmoid+bg).
// ---------------------------------------------------------------------------
__global__ __launch_bounds__(256, 4) void proj_gemm_kernel(
    const float* __restrict__ q_x, const float* __restrict__ k_x,
    const float* __restrict__ v_x, const _Float16* __restrict__ wT,
    const float* __restrict__ bg,
    _Float16* __restrict__ oq, _Float16* __restrict__ ok,
    _Float16* __restrict__ ov, _Float16* __restrict__ og)
{
    __shared__ _Float16 A_s[128][72];   // stride 72 f16 = 144B ≡ 4 banks mod 32
    __shared__ _Float16 B_s[128][72];
    const int z = blockIdx.z;
    const float* A = (z == 1) ? k_x : (z == 2) ? v_x : q_x;
    const _Float16* BT = wT + (size_t)z * 65536;
    _Float16* C = (z == 0) ? oq : (z == 1) ? ok : (z == 2) ? ov : og;
    const float scale = (z == 0) ? 0.17677669529663689f : 1.0f;

    const int m0 = blockIdx.x * 128, n0 = blockIdx.y * 128;
    const int tid = threadIdx.x;
    const int lane = tid & 63, w = tid >> 6;
    const int l15 = lane & 15, quad = lane >> 4;
    const int mw = (w & 1) * 64, nw = (w >> 1) * 64;

    f32x4 acc[4][4];
    #pragma unroll
    for (int mt = 0; mt < 4; ++mt)
        #pragma unroll
        for (int nt = 0; nt < 4; ++nt) acc[mt][nt] = (f32x4){0.f, 0.f, 0.f, 0.f};

    for (int k0 = 0; k0 < CIN; k0 += 64) {
        __syncthreads();
        #pragma unroll
        for (int it = 0; it < 4; ++it) {
            const int idx = tid + it * 256;     // 0..1023
            const int r = idx >> 3, seg = idx & 7;
            const float* ap = A + (size_t)(m0 + r) * CIN + k0 + seg * 8;
            const float4 f0 = *(const float4*)ap;
            const float4 f1 = *(const float4*)(ap + 4);
            f16x8 v;
            v[0] = (_Float16)f0.x; v[1] = (_Float16)f0.y;
            v[2] = (_Float16)f0.z; v[3] = (_Float16)f0.w;
            v[4] = (_Float16)f1.x; v[5] = (_Float16)f1.y;
            v[6] = (_Float16)f1.z; v[7] = (_Float16)f1.w;
            *(f16x8*)&A_s[r][seg * 8] = v;
            *(uint4*)&B_s[r][seg * 8] =
                *(const uint4*)(BT + (size_t)(n0 + r) * CIN + k0 + seg * 8);
        }
        __syncthreads();
        #pragma unroll
        for (int ks = 0; ks < 2; ++ks) {
            f16x8 af[4], bf[4];
            #pragma unroll
            for (int mt = 0; mt < 4; ++mt)
                af[mt] = *(const f16x8*)&A_s[mw + mt * 16 + l15][ks * 32 + quad * 8];
            #pragma unroll
            for (int nt = 0; nt < 4; ++nt)
                bf[nt] = *(const f16x8*)&B_s[nw + nt * 16 + l15][ks * 32 + quad * 8];
            #pragma unroll
            for (int mt = 0; mt < 4; ++mt)
                #pragma unroll
                for (int nt = 0; nt < 4; ++nt)
                    acc[mt][nt] = __builtin_amdgcn_mfma_f32_16x16x32_f16(
                        af[mt], bf[nt], acc[mt][nt], 0, 0, 0);
        }
    }

    #pragma unroll
    for (int mt = 0; mt < 4; ++mt) {
        #pragma unroll
        for (int nt = 0; nt < 4; ++nt) {
            const int col = n0 + nw + nt * 16 + l15;
            const int rowb = m0 + mw + mt * 16 + quad * 4;
            #pragma unroll
            for (int reg = 0; reg < 4; ++reg) {
                float x = acc[mt][nt][reg] * scale;
                if (z == 3) {
                    x += bg[col];
                    x = 1.0f / (1.0f + __expf(-x));
                }
                C[(size_t)(rowb + reg) * HIDDIM + col] = (_Float16)x;
            }
        }
    }
}

// ---------------------------------------------------------------------------
// Generic MFMA GEMM — final output projection (fp16 in, fp32 out + bias).
// ---------------------------------------------------------------------------
__global__ __launch_bounds__(256, 4) void gemm_mfma_kernel(
    const _Float16* __restrict__ Ain, const _Float16* __restrict__ BT,
    const float* __restrict__ bias, float* __restrict__ Cout)
{
    __shared__ _Float16 A_s[128][72];
    __shared__ _Float16 B_s[128][72];
    const int m0 = blockIdx.x * 128, n0 = blockIdx.y * 128;
    const int tid = threadIdx.x;
    const int lane = tid & 63, w = tid >> 6;
    const int l15 = lane & 15, quad = lane >> 4;
    const int mw = (w & 1) * 64, nw = (w >> 1) * 64;

    f32x4 acc[4][4];
    #pragma unroll
    for (int mt = 0; mt < 4; ++mt)
        #pragma unroll
        for (int nt = 0; nt < 4; ++nt) acc[mt][nt] = (f32x4){0.f, 0.f, 0.f, 0.f};

    for (int k0 = 0; k0 < CIN; k0 += 64) {
        __syncthreads();
        #pragma unroll
        for (int it = 0; it < 4; ++it) {
            const int idx = tid + it * 256;
            const int r = idx >> 3, seg = idx & 7;
            *(uint4*)&A_s[r][seg * 8] =
                *(const uint4*)(Ain + (size_t)(m0 + r) * CIN + k0 + seg * 8);
            *(uint4*)&B_s[r][seg * 8] =
                *(const uint4*)(BT + (size_t)(n0 + r) * CIN + k0 + seg * 8);
        }
        __syncthreads();
        #pragma unroll
        for (int ks = 0; ks < 2; ++ks) {
            f16x8 af[4], bf[4];
            #pragma unroll
            for (int mt = 0; mt < 4; ++mt)
                af[mt] = *(const f16x8*)&A_s[mw + mt * 16 + l15][ks * 32 + quad * 8];
            #pragma unroll
            for (int nt = 0; nt < 4; ++nt)
                bf[nt] = *(const f16x8*)&B_s[nw + nt * 16 + l15][ks * 32 + quad * 8];
            #pragma unroll
            for (int mt = 0; mt < 4; ++mt)
                #pragma unroll
                for (int nt = 0; nt < 4; ++nt)
                    acc[mt][nt] = __builtin_amdgcn_mfma_f32_16x16x32_f16(
                        af[mt], bf[nt], acc[mt][nt], 0, 0, 0);
        }
    }

    #pragma unroll
    for (int mt = 0; mt < 4; ++mt) {
        #pragma unroll
        for (int nt = 0; nt < 4; ++nt) {
            const int col = n0 + nw + nt * 16 + l15;
            const int rowb = m0 + mw + mt * 16 + quad * 4;
            #pragma unroll
            for (int reg = 0; reg < 4; ++reg) {
                const float x = acc[mt][nt][reg] + bias[col];
                Cout[(size_t)(rowb + reg) * HIDDIM + col] = x;
            }
        }
    }
}

// ---------------------------------------------------------------------------
// V transpose: v[n*512+k][h*32+c] fp16 -> vT[(n*8+h)*32+c][k 512] fp16.
// ---------------------------------------------------------------------------
__global__ __launch_bounds__(256) void vtrans_kernel(
    const _Float16* __restrict__ v, _Float16* __restrict__ vT)
{
    __shared__ _Float16 t[32][72];
    const int nh = blockIdx.x;
    const int n = nh >> 3, h = nh & 7;
    const int tid = threadIdx.x;
    for (int kc = 0; kc < KLEN; kc += 64) {
        __syncthreads();
        const int r = tid >> 2, c8 = (tid & 3) * 8;
        const f16x8 vv = *(const f16x8*)(v + (size_t)(n * KLEN + kc + r) * HIDDIM + h * CH + c8);
        #pragma unroll
        for (int j = 0; j < 8; ++j) t[c8 + j][r] = vv[j];
        __syncthreads();
        const int c = tid >> 3, k8 = (tid & 7) * 8;
        const f16x8 o = *(const f16x8*)&t[c][k8];
        *(f16x8*)(vT + ((size_t)nh * CH + c) * KLEN + kc + k8) = o;
    }
}

// ---------------------------------------------------------------------------
// MFMA flash attention, register-P (S^T trick), LDS-staged K/V, fragment-
// ordered bias_pair. Block = (n, h, 128 q-rows), 4 waves, 32 q-rows/wave.
// launch_bounds(256,4): 128-VGPR budget. (256,8) in r6 forced a 64-VGPR cap
// -> 330 MB of scratch-spill HBM writes and a 204us regression. 4 blocks/CU
// with no spill beats 8 blocks/CU with spills.
// ---------------------------------------------------------------------------
__global__ __launch_bounds__(256, 4) void attn_kernel(
    const _Float16* __restrict__ qb, const _Float16* __restrict__ kb,
    const _Float16* __restrict__ vT, const _Float16* __restrict__ gb,
    _Float16* __restrict__ ob,
    const float* __restrict__ bias_mask, const float* __restrict__ bp_frag)
{
    __shared__ _Float16 k_s[128][40];    // 80B rows ≡ 20 banks mod 32
    __shared__ _Float16 v_s[32][136];    // [c][k], 272B rows ≡ 4 banks mod 32

    const int n    = blockIdx.x;
    const int h    = blockIdx.y;
    const int q0   = blockIdx.z * 128;
    const int tid  = threadIdx.x;
    const int lane = tid & 63;
    const int wq   = tid >> 6;            // wave id: q-band = wq*32
    const int l15  = lane & 15;
    const int quad = lane >> 4;

    // Q fragments (B-operand of S^T): row q0+wq*32+qt*16+l15, cols quad*8..+7
    f16x8 qf[2];
    #pragma unroll
    for (int qt = 0; qt < 2; ++qt)
        qf[qt] = *(const f16x8*)(qb +
            (size_t)(n * QLEN + q0 + wq * 32 + qt * 16 + l15) * HIDDIM + h * CH + quad * 8);

    // Fragment-ordered bias base for this wave's first q-tile (qt adds 32*256).
    const float* bpf = bp_frag +
        ((size_t)(h * 32 + blockIdx.z * 8 + wq * 2) * 32) * 256 + lane * 4;
    const float* bmb = bias_mask + n * KLEN + quad * 4;

    f32x4 o_acc[2][2];
    float l_lane[2] = {0.f, 0.f};
    #pragma unroll
    for (int qt = 0; qt < 2; ++qt)
        #pragma unroll
        for (int ct = 0; ct < 2; ++ct) o_acc[qt][ct] = (f32x4){0.f, 0.f, 0.f, 0.f};

    const f32x4 z4 = (f32x4){0.f, 0.f, 0.f, 0.f};

    for (int ch = 0; ch < 4; ++ch) {
        __syncthreads();   // previous chunk fully consumed
        // Stage K chunk [128][32] and V chunk [32][128] (from pre-transposed vT),
        // both fully coalesced 16B/lane.
        #pragma unroll
        for (int i = 0; i < 2; ++i) {
            const int idx = tid + i * 256;
            const int r = idx >> 2, c8 = idx & 3;
            *(uint4*)&k_s[r][c8 * 8] = *(const uint4*)
                (kb + (size_t)(n * KLEN + ch * 128 + r) * HIDDIM + h * CH + c8 * 8);
            const int vr = idx >> 4, vs = idx & 15;
            *(uint4*)&v_s[vr][vs * 8] = *(const uint4*)
                (vT + ((size_t)(n * HEADS + h) * CH + vr) * KLEN + ch * 128 + vs * 8);
        }
        __syncthreads();

        #pragma unroll
        for (int kt = 0; kt < 8; ++kt) {
            const int kti = ch * 8 + kt;
            // K fragment (A-operand of S^T) from LDS.
            const f16x8 kf = *(const f16x8*)&k_s[kt * 16 + l15][quad * 8];
            const f32x4 s0 = __builtin_amdgcn_mfma_f32_16x16x32_f16(kf, qf[0], z4, 0, 0, 0);
            const f32x4 s1 = __builtin_amdgcn_mfma_f32_16x16x32_f16(kf, qf[1], z4, 0, 0, 0);
            const float4 bm = *(const float4*)(bmb + ch * 128 + kt * 16);
            // V fragments (B-operand of PV, K=16): k = quad*4+j, c = ct*16+l15
            const f16x4 bv0 = *(const f16x4*)&v_s[l15][kt * 16 + quad * 4];
            const f16x4 bv1 = *(const f16x4*)&v_s[16 + l15][kt * 16 + quad * 4];
            #pragma unroll
            for (int qt = 0; qt < 2; ++qt) {
                const f32x4 s = qt ? s1 : s0;
                const float4 bp = *(const float4*)(bpf + ((size_t)qt * 32 + kti) * 256);
                const float p0 = __expf(s[0] + bm.x + bp.x - 4.0f);
                const float p1 = __expf(s[1] + bm.y + bp.y - 4.0f);
                const float p2 = __expf(s[2] + bm.z + bp.z - 4.0f);
                const float p3 = __expf(s[3] + bm.w + bp.w - 4.0f);
                l_lane[qt] += (p0 + p1) + (p2 + p3);
                union { f16x4 v; fp16x2 h[2]; } u;
                u.h[0] = __builtin_amdgcn_cvt_pkrtz(p0, p1);
                u.h[1] = __builtin_amdgcn_cvt_pkrtz(p2, p3);
                o_acc[qt][0] = __builtin_amdgcn_mfma_f32_16x16x16f16(u.v, bv0, o_acc[qt][0], 0, 0, 0);
                o_acc[qt][1] = __builtin_amdgcn_mfma_f32_16x16x16f16(u.v, bv1, o_acc[qt][1], 0, 0, 0);
            }
        }
    }

    // Reduce l across quads (full row sum for q = qt*16+l15), then fetch the
    // values for this lane's OUTPUT rows (q = quad*4+reg) via shuffles.
    float invl[2][4];
    #pragma unroll
    for (int qt = 0; qt < 2; ++qt) {
        float lf = l_lane[qt];
        lf += __shfl_xor(lf, 16);
        lf += __shfl_xor(lf, 32);
        #pragma unroll
        for (int reg = 0; reg < 4; ++reg)
            invl[qt][reg] = 1.0f / __shfl(lf, quad * 4 + reg);
    }

    // Epilogue: O D-layout col=l15 -> c, row=quad*4+reg -> q. Gate + store.
    #pragma unroll
    for (int qt = 0; qt < 2; ++qt) {
        #pragma unroll
        for (int ct = 0; ct < 2; ++ct) {
            #pragma unroll
            for (int reg = 0; reg < 4; ++reg) {
                const int row = q0 + wq * 32 + qt * 16 + quad * 4 + reg;
                const size_t idx = (size_t)(n * QLEN + row) * HIDDIM + h * CH + ct * 16 + l15;
                const float g = (float)gb[idx];
                ob[idx] = (_Float16)(o_acc[qt][ct][reg] * invl[qt][reg] * g);
            }
        }
    }
}

// ---------------------------------------------------------------------------
// Launch: wcast + bpfrag -> projections -> V transpose -> attention -> out GEMM.
// Workspace: 6 x 16.8 MB fp16 + 0.66 MB weights + 8.4 MB bp_frag = 110 MB
// ---------------------------------------------------------------------------
extern "C" void kernel_launch(void* const* d_in, const int* in_sizes, int n_in,
                              void* d_out, int out_size, void* d_ws, size_t ws_size,
                              hipStream_t stream)
{
    const float* q_x       = (const float*)d_in[0];
    const float* k_x       = (const float*)d_in[1];
    const float* v_x       = (const float*)d_in[2];
    const float* bias_mask = (const float*)d_in[3];
    const float* bias_pair = (const float*)d_in[4];
    const float* wq        = (const float*)d_in[5];
    const float* wk        = (const float*)d_in[6];
    const float* wv        = (const float*)d_in[7];
    const float* wg        = (const float*)d_in[8];
    const float* bg        = (const float*)d_in[9];
    const float* wo        = (const float*)d_in[10];
    const float* bo        = (const float*)d_in[11];
    float* out = (float*)d_out;

    const size_t BUF = (size_t)M_TOTAL * HIDDIM;   // 8388608 elems
    _Float16* ws_q  = (_Float16*)d_ws;
    _Float16* ws_k  = ws_q + BUF;
    _Float16* ws_v  = ws_k + BUF;
    _Float16* ws_vT = ws_v + BUF;
    _Float16* ws_g  = ws_vT + BUF;
    _Float16* ws_o  = ws_g + BUF;
    _Float16* wT    = ws_o + BUF;                  // 5 x 256*256 fp16
    float*    bpf   = (float*)(wT + 5 * 65536);    // 8 x 512 x 512 fp32 frag-ordered

    wcast_kernel<<<dim3(4, 4, 5), 256, 0, stream>>>(wq, wk, wv, wg, wo, wT);
    bpfrag_kernel<<<dim3(8, 8, 8), 256, 0, stream>>>(bias_pair, bpf);

    proj_gemm_kernel<<<dim3(M_TOTAL / 128, 2, 4), 256, 0, stream>>>(
        q_x, k_x, v_x, wT, bg, ws_q, ws_k, ws_v, ws_g);

    vtrans_kernel<<<dim3(NSEQ * HEADS), 256, 0, stream>>>(ws_v, ws_vT);

    attn_kernel<<<dim3(NSEQ, HEADS, QLEN / 128), 256, 0, stream>>>(
        ws_q, ws_k, ws_vT, ws_g, ws_o, bias_mask, bpf);

    gemm_mfma_kernel<<<dim3(M_TOTAL / 128, 2), 256, 0, stream>>>(
        ws_o, wT + 4 * 65536, bo, out);
}